// Round 8
// baseline (153.467 us; speedup 1.0000x reference)
//
#include <hip/hip_runtime.h>
#include <hip/hip_bf16.h>
#include <math.h>

#define NN 8192
#define NFEAT 1433
#define NHID 64
#define NCLASS 7
#define CAP 96

#define KSPLIT 8
#define KCHUNK 192        // 8*192 = 1536 >= 1433; up to 6 k-steps of 32 per chunk
#define NB_GEMM 1024      // 128 tiles x 8 k-chunks

typedef float f32x4 __attribute__((ext_vector_type(4)));
typedef short bf16x8 __attribute__((ext_vector_type(8)));

__device__ __forceinline__ ushort f2bf(float f) {
    __hip_bfloat16 h = __float2bfloat16(f);
    return *reinterpret_cast<ushort*>(&h);
}

// ---------------------------------------------------------------------------
// k_scan: pure adjacency stream. One wave per row, depth-8 rolling register
// prefetch (8 x 1KB wave-loads in flight), ballot-compaction of column
// indices. No LDS, no syncthreads, no P access — structured like a memcpy.
// ---------------------------------------------------------------------------
__global__ __launch_bounds__(256, 8) void k_scan(const float* __restrict__ adj,
                                                 int* __restrict__ cnt,
                                                 int* __restrict__ cols) {
    const int wave = threadIdx.x >> 6;
    const int lane = threadIdx.x & 63;
    const int row  = blockIdx.x * 4 + wave;

    const f32x4* arow4 = (const f32x4*)(adj + (size_t)row * NN);
    const unsigned long long lt = (1ull << lane) - 1ull;
    const size_t rowCAP = (size_t)row * CAP;
    int base = 0;

    f32x4 buf[8];
    #pragma unroll
    for (int i = 0; i < 8; ++i) buf[i] = arow4[i * 64 + lane];

    for (int g = 0; g < 4; ++g) {              // outer loop NOT unrolled
        #pragma unroll
        for (int u = 0; u < 8; ++u) {          // buf index compile-time const
            const int it = g * 8 + u;
            f32x4 cur = buf[u];
            if (g < 3) buf[u] = arow4[(it + 8) * 64 + lane];
            const int jb = (it * 64 + lane) * 4;
            #pragma unroll
            for (int s = 0; s < 4; ++s) {
                bool nz = (cur[s] != 0.f);
                unsigned long long mask = __ballot(nz);
                if (nz) {
                    int pos = base + __popcll(mask & lt);
                    if (pos < CAP) cols[rowCAP + pos] = jb + s;
                }
                base += __popcll(mask);
            }
        }
    }
    if (lane == 0) cnt[row] = (base < CAP) ? base : CAP;
}

// ---------------------------------------------------------------------------
// k_pdinv: lane-parallel P gather + sigmoid + degree. One wave per row.
// ---------------------------------------------------------------------------
__global__ __launch_bounds__(256) void k_pdinv(const float* __restrict__ P,
                                               const int* __restrict__ cnt,
                                               const int* __restrict__ cols,
                                               float* __restrict__ vals,
                                               float* __restrict__ dinv) {
    const int wave = threadIdx.x >> 6;
    const int lane = threadIdx.x & 63;
    const int row  = blockIdx.x * 4 + wave;

    const long tb = (long)row * (row + 1) / 2;
    const size_t rowCAP = (size_t)row * CAP;
    const int c = cnt[row];
    float dsum = 0.f;
    for (int k = lane; k < c; k += 64) {       // c <= 96 -> at most 2 iters
        int j = cols[rowCAP + k];
        long pidx = (j <= row) ? (tb + j) : ((long)j * (j + 1) / 2 + row);
        float p = P[pidx];
        float v = 1.f / (1.f + __expf(-p));
        vals[rowCAP + k] = v;
        dsum += v;
    }
    #pragma unroll
    for (int s = 32; s; s >>= 1) dsum += __shfl_xor(dsum, s, 64);
    if (lane == 0) dinv[row] = 1.f / sqrtf(1.f + dsum);
}

// ---------------------------------------------------------------------------
// k_gemm: XW1 partials via bf16 MFMA 16x16x32 (round-6 proven GEMM role).
// 64x64 tile x 192-K chunk per block; W1 converted to bf16 inline.
// ---------------------------------------------------------------------------
__global__ __launch_bounds__(256, 8) void k_gemm(const float* __restrict__ x,
                                                 const float* __restrict__ W1,
                                                 float* __restrict__ part) {
    __shared__ __align__(16) ushort xa[64][40];
    __shared__ __align__(16) ushort wt[64][40];

    const int t = threadIdx.x;
    const int tile = blockIdx.x >> 3;     // 0..127
    const int ks   = blockIdx.x & 7;      // 0..7
    const int m0 = tile * 64;
    const int k_begin = ks * KCHUNK;
    const int k_end   = (k_begin + KCHUNK < NFEAT) ? k_begin + KCHUNK : NFEAT;
    const int l = t & 63;
    const int w = t >> 6;

    const int sr  = t >> 2;               // 0..63
    const int sc8 = (t & 3) * 8;          // 0,8,16,24
    const float* xrow = x + (size_t)(m0 + sr) * NFEAT;
    const int wc  = t & 63;
    const int wk8 = (t >> 6) * 8;
    const int arow = w * 16 + (l & 15);
    const int kb   = (l >> 4) * 8;

    f32x4 acc[4];
    #pragma unroll
    for (int ct = 0; ct < 4; ++ct) acc[ct] = (f32x4){0.f, 0.f, 0.f, 0.f};

    for (int k0 = k_begin; k0 < k_end; k0 += 32) {
        uint4 xp;
        {
            ushort u[8];
            #pragma unroll
            for (int jj = 0; jj < 8; ++jj) {
                int k = k0 + sc8 + jj;
                u[jj] = f2bf((k < k_end) ? xrow[k] : 0.f);
            }
            xp.x = (unsigned)u[0] | ((unsigned)u[1] << 16);
            xp.y = (unsigned)u[2] | ((unsigned)u[3] << 16);
            xp.z = (unsigned)u[4] | ((unsigned)u[5] << 16);
            xp.w = (unsigned)u[6] | ((unsigned)u[7] << 16);
        }
        *(uint4*)(&xa[sr][sc8]) = xp;
        uint4 wp;
        {
            ushort u[8];
            #pragma unroll
            for (int jj = 0; jj < 8; ++jj) {
                int k = k0 + wk8 + jj;
                u[jj] = f2bf((k < k_end) ? W1[(size_t)k * 64 + wc] : 0.f);
            }
            wp.x = (unsigned)u[0] | ((unsigned)u[1] << 16);
            wp.y = (unsigned)u[2] | ((unsigned)u[3] << 16);
            wp.z = (unsigned)u[4] | ((unsigned)u[5] << 16);
            wp.w = (unsigned)u[6] | ((unsigned)u[7] << 16);
        }
        *(uint4*)(&wt[wc][wk8]) = wp;
        __syncthreads();

        bf16x8 af = *(const bf16x8*)(&xa[arow][kb]);
        #pragma unroll
        for (int ct = 0; ct < 4; ++ct) {
            bf16x8 bfr = *(const bf16x8*)(&wt[ct * 16 + (l & 15)][kb]);
            acc[ct] = __builtin_amdgcn_mfma_f32_16x16x32_bf16(af, bfr, acc[ct], 0, 0, 0);
        }
        __syncthreads();
    }
    // C/D mapping col=lane&15, row=(lane>>4)*4+reg (m89-verified)
    float* pout = part + (size_t)ks * NN * NHID;
    const int orow = m0 + w * 16 + ((l >> 4) << 2);
    const int ocol = l & 15;
    #pragma unroll
    for (int ct = 0; ct < 4; ++ct)
        #pragma unroll
        for (int rix = 0; rix < 4; ++rix)
            pout[(size_t)(orow + rix) * 64 + ct * 16 + ocol] = acc[ct][rix];
}

// ---------------------------------------------------------------------------
// Reduce the 8 K-split partials into XW1 (float4, fully coalesced).
// ---------------------------------------------------------------------------
__global__ __launch_bounds__(256) void k_reduce(const float* __restrict__ part,
                                                float* __restrict__ XW1) {
    const size_t i4 = (size_t)blockIdx.x * 256 + threadIdx.x;
    const f32x4* p4 = (const f32x4*)part;
    f32x4 s = p4[i4];
    #pragma unroll
    for (int ks = 1; ks < KSPLIT; ++ks)
        s += p4[(size_t)ks * (NN * NHID / 4) + i4];
    ((f32x4*)XW1)[i4] = s;
}

// ---------------------------------------------------------------------------
// spmm1: h1 = relu(dinv_i*(dinv_i*XW1_i + sum_j v*dinv_j*XW1_j) + b1),
// fused HW2 = h1 @ W2. One wave per row; depth-2 value pipeline.
// ---------------------------------------------------------------------------
__global__ __launch_bounds__(256) void k_spmm1(const float* __restrict__ XW1,
                                               const float* __restrict__ dinv,
                                               const int* __restrict__ cnt,
                                               const int* __restrict__ cols,
                                               const float* __restrict__ vals,
                                               const float* __restrict__ b1,
                                               const float* __restrict__ W2,
                                               float* __restrict__ HW2) {
    const int wave = threadIdx.x >> 6;
    const int lane = threadIdx.x & 63;
    const int row  = blockIdx.x * 4 + wave;
    if (row >= NN) return;

    const float di = dinv[row];
    float acc = di * XW1[(size_t)row * NHID + lane];
    const int c = cnt[row];
    const int*   cp = cols + (size_t)row * CAP;
    const float* vp = vals + (size_t)row * CAP;

    int j0 = 0, j1 = 0; float v0 = 0.f, v1 = 0.f, w0 = 0.f, w1 = 0.f, d0 = 0.f, d1 = 0.f;
    if (c > 0) { j0 = cp[0]; v0 = vp[0]; w0 = XW1[(size_t)j0 * NHID + lane]; d0 = dinv[j0]; }
    if (c > 1) { j1 = cp[1]; v1 = vp[1]; w1 = XW1[(size_t)j1 * NHID + lane]; d1 = dinv[j1]; }
    for (int k = 0; k < c; ++k) {
        acc += v0 * d0 * w0;
        j0 = j1; v0 = v1; w0 = w1; d0 = d1;
        if (k + 2 < c) {
            int jn = cp[k + 2];
            j1 = jn; v1 = vp[k + 2];
            w1 = XW1[(size_t)jn * NHID + lane];
            d1 = dinv[jn];
        }
    }
    float h1 = di * acc + b1[lane];
    h1 = fmaxf(h1, 0.f);

    float o[NCLASS];
    #pragma unroll
    for (int cc = 0; cc < NCLASS; ++cc) o[cc] = h1 * W2[lane * NCLASS + cc];
    #pragma unroll
    for (int cc = 0; cc < NCLASS; ++cc)
        for (int s = 32; s; s >>= 1) o[cc] += __shfl_xor(o[cc], s, 64);
    if (lane == 0) {
        #pragma unroll
        for (int cc = 0; cc < NCLASS; ++cc)
            HW2[(size_t)row * NCLASS + cc] = o[cc];
    }
}

// ---------------------------------------------------------------------------
// spmm2: h2 = norm_adj @ HW2 + b2 -> log_softmax. One wave per row.
// ---------------------------------------------------------------------------
__global__ __launch_bounds__(256) void k_spmm2(const float* __restrict__ HW2,
                                               const float* __restrict__ dinv,
                                               const int* __restrict__ cnt,
                                               const int* __restrict__ cols,
                                               const float* __restrict__ vals,
                                               const float* __restrict__ b2,
                                               float* __restrict__ out) {
    const int wave = threadIdx.x >> 6;
    const int lane = threadIdx.x & 63;
    const int row  = blockIdx.x * 4 + wave;
    if (row >= NN) return;

    const int c = cnt[row];
    const int*   cp = cols + (size_t)row * CAP;
    const float* vp = vals + (size_t)row * CAP;
    float acc[NCLASS] = {};
    for (int k = lane; k < c; k += 64) {
        int j   = cp[k];
        float wgt = vp[k] * dinv[j];
        #pragma unroll
        for (int cc = 0; cc < NCLASS; ++cc)
            acc[cc] += wgt * HW2[(size_t)j * NCLASS + cc];
    }
    #pragma unroll
    for (int cc = 0; cc < NCLASS; ++cc)
        for (int s = 32; s; s >>= 1) acc[cc] += __shfl_xor(acc[cc], s, 64);

    if (lane == 0) {
        const float di = dinv[row];
        float h[NCLASS], m = -1e30f;
        #pragma unroll
        for (int cc = 0; cc < NCLASS; ++cc) {
            h[cc] = di * (acc[cc] + di * HW2[(size_t)row * NCLASS + cc]) + b2[cc];
            m = fmaxf(m, h[cc]);
        }
        float s = 0.f;
        #pragma unroll
        for (int cc = 0; cc < NCLASS; ++cc) s += expf(h[cc] - m);
        float lse = m + logf(s);
        #pragma unroll
        for (int cc = 0; cc < NCLASS; ++cc)
            out[(size_t)row * NCLASS + cc] = h[cc] - lse;
    }
}

// ---------------------------------------------------------------------------
extern "C" void kernel_launch(void* const* d_in, const int* in_sizes, int n_in,
                              void* d_out, int out_size, void* d_ws, size_t ws_size,
                              hipStream_t stream) {
    const float* x   = (const float*)d_in[0];
    const float* adj = (const float*)d_in[1];
    const float* P   = (const float*)d_in[2];
    const float* W1  = (const float*)d_in[3];
    const float* b1  = (const float*)d_in[4];
    const float* W2  = (const float*)d_in[5];
    const float* b2  = (const float*)d_in[6];
    float* out = (float*)d_out;

    char* ws = (char*)d_ws;
    size_t off = 0;
    float* dinv = (float*)(ws + off);  off += (size_t)NN * 4;
    int*   cnt  = (int*)  (ws + off);  off += (size_t)NN * 4;
    int*   cols = (int*)  (ws + off);  off += (size_t)NN * CAP * 4;
    float* vals = (float*)(ws + off);  off += (size_t)NN * CAP * 4;
    float* XW1  = (float*)(ws + off);  off += (size_t)NN * NHID * 4;
    float* HW2  = (float*)(ws + off);  off += (size_t)NN * NCLASS * 4;
    float* part = (float*)(ws + off);  off += (size_t)KSPLIT * NN * NHID * 4;

    k_scan <<<dim3(NN / 4), dim3(256), 0, stream>>>(adj, cnt, cols);
    k_pdinv<<<dim3(NN / 4), dim3(256), 0, stream>>>(P, cnt, cols, vals, dinv);
    k_gemm <<<dim3(NB_GEMM), dim3(256), 0, stream>>>(x, W1, part);
    k_reduce<<<dim3(NN * NHID / 4 / 256), dim3(256), 0, stream>>>(part, XW1);
    k_spmm1<<<dim3(NN / 4), dim3(256), 0, stream>>>(XW1, dinv, cnt, cols, vals, b1, W2, HW2);
    k_spmm2<<<dim3(NN / 4), dim3(256), 0, stream>>>(HW2, dinv, cnt, cols, vals, b2, out);
}